// Round 1
// baseline (864.182 us; speedup 1.0000x reference)
//
#include <hip/hip_runtime.h>

#define NB 256
#define NN 64
#define NT 4096

// K1: variance per (b,i) row over 4096 elements, ddof=1.
__global__ __launch_bounds__(256) void var_kernel(const float* __restrict__ x,
                                                  float* __restrict__ e) {
    int row = blockIdx.x;  // b*64 + i
    const float4* xr = (const float4*)(x + (size_t)row * NT);
    int tid = threadIdx.x;
    float s = 0.f, ss = 0.f;
#pragma unroll
    for (int k = 0; k < 4; ++k) {
        float4 v = xr[tid + k * 256];
        s  += (v.x + v.y) + (v.z + v.w);
        ss += (v.x * v.x + v.y * v.y) + (v.z * v.z + v.w * v.w);
    }
#pragma unroll
    for (int off = 32; off > 0; off >>= 1) {
        s  += __shfl_down(s, off);
        ss += __shfl_down(ss, off);
    }
    __shared__ float sh[8];
    int w = tid >> 6;
    if ((tid & 63) == 0) { sh[w] = s; sh[4 + w] = ss; }
    __syncthreads();
    if (tid == 0) {
        float S  = (sh[0] + sh[1]) + (sh[2] + sh[3]);
        float SS = (sh[4] + sh[5]) + (sh[6] + sh[7]);
        float mean = S * (1.0f / NT);
        e[row] = (SS - (float)NT * mean * mean) * (1.0f / (NT - 1));
    }
}

// K2: softmax attention weights per batch. Logits factor as
// SCALE*(A*e_i*e_j + Bq*e_i + Bk*e_j + C). One thread per row i.
__global__ __launch_bounds__(64) void attn_kernel(const float* __restrict__ e,
                                                  const float* __restrict__ wq,
                                                  const float* __restrict__ bq,
                                                  const float* __restrict__ wk,
                                                  const float* __restrict__ bk,
                                                  float* __restrict__ attn_out) {
    int b = blockIdx.x;
    int i = threadIdx.x;
    float A = 0.f, Bq = 0.f, Bk = 0.f, C = 0.f;
#pragma unroll
    for (int h = 0; h < 16; ++h) {
        A  += wq[h] * wk[h];
        Bq += wq[h] * bk[h];
        Bk += bq[h] * wk[h];
        C  += bq[h] * bk[h];
    }
    __shared__ float es[NN];
    es[i] = e[b * NN + i];
    __syncthreads();
    float ei = es[i];
    float l[NN];
    float m = -3.0e38f;
#pragma unroll
    for (int j = 0; j < NN; ++j) {
        float v = 0.25f * (A * ei * es[j] + Bq * ei + Bk * es[j] + C);
        if (j == i) v = -1.0e9f;   // diagonal mask
        l[j] = v;
        m = fmaxf(m, v);
    }
    float sum = 0.f;
#pragma unroll
    for (int j = 0; j < NN; ++j) {
        float ev = expf(l[j] - m);  // diagonal underflows to exactly 0
        l[j] = ev;
        sum += ev;
    }
    float inv = 1.0f / sum;
    float* dst = attn_out + (size_t)b * (NN * NN) + i * NN;
#pragma unroll
    for (int j = 0; j < NN; ++j) dst[j] = l[j] * inv;
}

// K3: out[b,i,t] = x[b,i,t] + sum_j W[b,i,j] * x[b,j,t].
// One block = (batch, 128-column chunk). Each thread owns one column t:
// 64 x-values in registers (static indices via full unroll); W rows are
// wave-uniform -> scalar loads; dynamic x[i] residual comes from a private
// LDS mirror (no cross-thread sharing, avoids register-array scratch spill).
__global__ __launch_bounds__(128) void out_kernel(const float* __restrict__ x,
                                                  const float* __restrict__ W,
                                                  float* __restrict__ out) {
    int blk = blockIdx.x;
    int b = blk >> 5;        // 32 chunks of 128 columns per batch
    int chunk = blk & 31;
    int tid = threadIdx.x;
    int t = chunk * 128 + tid;
    const float* xb = x + (size_t)b * (NN * NT) + t;

    __shared__ float xs[NN][128];
    float xv[NN];
#pragma unroll
    for (int j = 0; j < NN; ++j) {
        float v = xb[(size_t)j * NT];
        xv[j] = v;
        xs[j][tid] = v;
    }
    __syncthreads();

    const float* Wb = W + (size_t)b * (NN * NN);
    float* ob = out + (size_t)b * (NN * NT) + t;
    for (int i = 0; i < NN; ++i) {
        const float* Wr = Wb + i * NN;   // uniform address -> s_load
        float acc = xs[i][tid];          // residual x[b,i,t] (W[i][i]==0)
#pragma unroll
        for (int j = 0; j < NN; ++j) acc = fmaf(Wr[j], xv[j], acc);
        ob[(size_t)i * NT] = acc;
    }
}

extern "C" void kernel_launch(void* const* d_in, const int* in_sizes, int n_in,
                              void* d_out, int out_size, void* d_ws, size_t ws_size,
                              hipStream_t stream) {
    const float* x  = (const float*)d_in[0];
    const float* wq = (const float*)d_in[1];
    const float* bq = (const float*)d_in[2];
    const float* wk = (const float*)d_in[3];
    const float* bk = (const float*)d_in[4];
    float* out  = (float*)d_out;
    float* attn = out + (size_t)NB * NN * NT;  // second output region
    float* e    = (float*)d_ws;                // 16384 floats scratch

    var_kernel<<<NB * NN, 256, 0, stream>>>(x, e);
    attn_kernel<<<NB, 64, 0, stream>>>(e, wq, bq, wk, bk, attn);
    out_kernel<<<NB * 32, 128, 0, stream>>>(x, attn, out);
}

// Round 2
// 577.730 us; speedup vs baseline: 1.4958x; 1.4958x over previous
//
#include <hip/hip_runtime.h>

#define NB 256
#define NN 64
#define NT 4096

// K1: variance per (b,i) row over 4096 elements, ddof=1.
__global__ __launch_bounds__(256) void var_kernel(const float* __restrict__ x,
                                                  float* __restrict__ e) {
    int row = blockIdx.x;  // b*64 + i
    const float4* xr = (const float4*)(x + (size_t)row * NT);
    int tid = threadIdx.x;
    float s = 0.f, ss = 0.f;
#pragma unroll
    for (int k = 0; k < 4; ++k) {
        float4 v = xr[tid + k * 256];
        s  += (v.x + v.y) + (v.z + v.w);
        ss += (v.x * v.x + v.y * v.y) + (v.z * v.z + v.w * v.w);
    }
#pragma unroll
    for (int off = 32; off > 0; off >>= 1) {
        s  += __shfl_down(s, off);
        ss += __shfl_down(ss, off);
    }
    __shared__ float sh[8];
    int w = tid >> 6;
    if ((tid & 63) == 0) { sh[w] = s; sh[4 + w] = ss; }
    __syncthreads();
    if (tid == 0) {
        float S  = (sh[0] + sh[1]) + (sh[2] + sh[3]);
        float SS = (sh[4] + sh[5]) + (sh[6] + sh[7]);
        float mean = S * (1.0f / NT);
        e[row] = (SS - (float)NT * mean * mean) * (1.0f / (NT - 1));
    }
}

// K2: softmax attention weights per batch. Logits factor as
// SCALE*(A*e_i*e_j + Bq*e_i + Bk*e_j + C). One thread per row i.
// Writes attn to d_out AND W' = attn + I to workspace (diagonal softmax
// weight is exactly 0 since exp(-1e9 - m) underflows, so W'[i][i] = 1
// exactly). W' lets out_kernel fold the residual into the dot product.
__global__ __launch_bounds__(64) void attn_kernel(const float* __restrict__ e,
                                                  const float* __restrict__ wq,
                                                  const float* __restrict__ bq,
                                                  const float* __restrict__ wk,
                                                  const float* __restrict__ bk,
                                                  float* __restrict__ attn_out,
                                                  float* __restrict__ wprime) {
    int b = blockIdx.x;
    int i = threadIdx.x;
    float A = 0.f, Bq = 0.f, Bk = 0.f, C = 0.f;
#pragma unroll
    for (int h = 0; h < 16; ++h) {
        A  += wq[h] * wk[h];
        Bq += wq[h] * bk[h];
        Bk += bq[h] * wk[h];
        C  += bq[h] * bk[h];
    }
    __shared__ float es[NN];
    es[i] = e[b * NN + i];
    __syncthreads();
    float ei = es[i];
    float l[NN];
    float m = -3.0e38f;
#pragma unroll
    for (int j = 0; j < NN; ++j) {
        float v = 0.25f * (A * ei * es[j] + Bq * ei + Bk * es[j] + C);
        if (j == i) v = -1.0e9f;   // diagonal mask
        l[j] = v;
        m = fmaxf(m, v);
    }
    float sum = 0.f;
#pragma unroll
    for (int j = 0; j < NN; ++j) {
        float ev = expf(l[j] - m);  // diagonal underflows to exactly 0
        l[j] = ev;
        sum += ev;
    }
    float inv = 1.0f / sum;
    float* dst = attn_out + (size_t)b * (NN * NN) + i * NN;
    float* wp  = wprime   + (size_t)b * (NN * NN) + i * NN;
#pragma unroll
    for (int j = 0; j < NN; ++j) {
        float w = l[j] * inv;
        dst[j] = w;
        wp[j]  = (j == i) ? 1.0f : w;  // fold residual identity
    }
}

// K3: out[b,i,t] = sum_j W'[b,i,j] * x[b,j,t]   (W' = attn + I).
// One block = (batch, 128-column chunk); thread owns column t with all 64
// x-values in registers (fully unrolled -> static indices). No LDS ->
// occupancy is VGPR-bound (~5-6 waves/SIMD). 4 independent accumulator
// chains per iteration (4 output rows) hide the 4-cyc FMA latency.
// W' rows are wave-uniform -> scalar s_loads.
__global__ __launch_bounds__(128) void out_kernel(const float* __restrict__ x,
                                                  const float* __restrict__ Wp,
                                                  float* __restrict__ out) {
    int blk = blockIdx.x;
    int b = blk >> 5;        // 32 chunks of 128 columns per batch
    int chunk = blk & 31;
    int t = chunk * 128 + threadIdx.x;
    const float* xb = x + (size_t)b * (NN * NT) + t;

    float xv[NN];
#pragma unroll
    for (int j = 0; j < NN; ++j) xv[j] = xb[(size_t)j * NT];

    const float* Wb = Wp + (size_t)b * (NN * NN);
    float* ob = out + (size_t)b * (NN * NT) + t;

#pragma unroll 1
    for (int i = 0; i < NN; i += 4) {
        const float* W0 = Wb + (i + 0) * NN;  // uniform -> s_load
        const float* W1 = Wb + (i + 1) * NN;
        const float* W2 = Wb + (i + 2) * NN;
        const float* W3 = Wb + (i + 3) * NN;
        float a0 = 0.f, a1 = 0.f, a2 = 0.f, a3 = 0.f;
#pragma unroll
        for (int j = 0; j < NN; ++j) {
            float v = xv[j];
            a0 = fmaf(W0[j], v, a0);
            a1 = fmaf(W1[j], v, a1);
            a2 = fmaf(W2[j], v, a2);
            a3 = fmaf(W3[j], v, a3);
        }
        ob[(size_t)(i + 0) * NT] = a0;
        ob[(size_t)(i + 1) * NT] = a1;
        ob[(size_t)(i + 2) * NT] = a2;
        ob[(size_t)(i + 3) * NT] = a3;
    }
}

extern "C" void kernel_launch(void* const* d_in, const int* in_sizes, int n_in,
                              void* d_out, int out_size, void* d_ws, size_t ws_size,
                              hipStream_t stream) {
    const float* x  = (const float*)d_in[0];
    const float* wq = (const float*)d_in[1];
    const float* bq = (const float*)d_in[2];
    const float* wk = (const float*)d_in[3];
    const float* bk = (const float*)d_in[4];
    float* out  = (float*)d_out;
    float* attn = out + (size_t)NB * NN * NT;     // second output region
    float* e    = (float*)d_ws;                   // 16384 floats
    float* wp   = (float*)d_ws + NB * NN;         // W' = attn + I, 4 MB

    var_kernel<<<NB * NN, 256, 0, stream>>>(x, e);
    attn_kernel<<<NB, 64, 0, stream>>>(e, wq, bq, wk, bk, attn, wp);
    out_kernel<<<NB * 32, 128, 0, stream>>>(x, wp, out);
}